// Round 2
// baseline (385.525 us; speedup 1.0000x reference)
//
#include <hip/hip_runtime.h>
#include <math.h>

#define NN 20000
#define EE 320000
#define FF 128
#define HH 256
#define HPITCH 264   // 256 + 8 bf16 pad
#define WPITCH 72    // 64 + 8 bf16 pad
#define MT 128       // edges per block
#define NTHREADS 512

typedef __bf16 bf16x8 __attribute__((ext_vector_type(8)));
typedef float  f32x4  __attribute__((ext_vector_type(4)));

// ---- workspace layout (floats/bf16 elements) ----
// accum : NN*FF fp32                     @ 0
// cnt   : NN fp32                        @ 10,240,000 B
// xb    : NN*FF bf16                     @ 10,320,000 B
// W1b   : HH*HH bf16                     @ 15,440,000 B
// W2b   : HH*HH bf16                     @ 15,571,072 B
// W3b   : FF*HH bf16                     @ 15,702,144 B   (end 15,767,680 B)
#define XB_OFF   10320000
#define W1B_OFF  15440000
#define W2B_OFF  15571072
#define W3B_OFF  15702144

#define CVT_TOTAL (NN*FF + HH*HH + HH*HH + FF*HH)   // 2,723,840 elements

__global__ __launch_bounds__(256) void convert_kernel(
    const float* __restrict__ x,  const float* __restrict__ W1,
    const float* __restrict__ W2, const float* __restrict__ W3,
    __bf16* __restrict__ xb, __bf16* __restrict__ w1b,
    __bf16* __restrict__ w2b, __bf16* __restrict__ w3b)
{
    const size_t base = ((size_t)blockIdx.x * 256 + threadIdx.x) * 4;
    if (base >= CVT_TOTAL) return;
    const float* src; __bf16* dst; size_t off;
    if (base < (size_t)NN * FF)                { src = x;  dst = xb;  off = base; }
    else if (base < (size_t)NN*FF + HH*HH)     { src = W1; dst = w1b; off = base - (size_t)NN*FF; }
    else if (base < (size_t)NN*FF + 2*HH*HH)   { src = W2; dst = w2b; off = base - (size_t)NN*FF - HH*HH; }
    else                                       { src = W3; dst = w3b; off = base - (size_t)NN*FF - 2*HH*HH; }
    float4 v = *(const float4*)(src + off);
    __bf16 o[4] = { (__bf16)v.x, (__bf16)v.y, (__bf16)v.z, (__bf16)v.w };
    __builtin_memcpy(dst + off, o, 8);
}

__global__ __launch_bounds__(NTHREADS) void fused_edge_mlp(
    const __bf16* __restrict__ x,
    const int*    __restrict__ eidx,
    const __bf16* __restrict__ W1,
    const float*  __restrict__ b1, const float* __restrict__ g1,
    const float*  __restrict__ be1, const float* __restrict__ rm1,
    const float*  __restrict__ rv1,
    const __bf16* __restrict__ W2,
    const float*  __restrict__ b2, const float* __restrict__ g2,
    const float*  __restrict__ be2, const float* __restrict__ rm2,
    const float*  __restrict__ rv2,
    const __bf16* __restrict__ W3, const float* __restrict__ b3,
    float* __restrict__ accum, float* __restrict__ cnt)
{
    __shared__ __align__(16) __bf16 sh_h[MT * HPITCH];   // 67584 B
    __shared__ __align__(16) __bf16 sh_w[HH * WPITCH];   // 36864 B
    __shared__ float s_scale[2][HH];
    __shared__ float s_c[2][HH];
    __shared__ float s_b3[FF];
    __shared__ int   s_dst[MT];
    __shared__ int   s_src[MT];

    const int tid = threadIdx.x;
    const int e0  = blockIdx.x * MT;

    if (tid < MT) {
        s_src[tid] = eidx[e0 + tid];        // edge_index[0] = src
        s_dst[tid] = eidx[EE + e0 + tid];   // edge_index[1] = dst
    }
    if (tid < HH) {
        float sc1 = g1[tid] * rsqrtf(rv1[tid] + 1e-5f);
        s_scale[0][tid] = sc1;
        s_c[0][tid] = (b1[tid] - rm1[tid]) * sc1 + be1[tid];
        float sc2 = g2[tid] * rsqrtf(rv2[tid] + 1e-5f);
        s_scale[1][tid] = sc2;
        s_c[1][tid] = (b2[tid] - rm2[tid]) * sc2 + be2[tid];
        if (tid < FF) s_b3[tid] = b3[tid];
    }
    __syncthreads();

    // ---- gather & concat: sh_h[r][0:128] = x[dst], sh_h[r][128:256] = x[src]-x[dst]
    {
        const int r = tid >> 2;       // 0..127
        const int q = tid & 3;        // 32-col quarter
        const __bf16* xd = x + (size_t)s_dst[r] * FF + q * 32;
        const __bf16* xs = x + (size_t)s_src[r] * FF + q * 32;
        uint4 di[4], sj[4];
        #pragma unroll
        for (int i = 0; i < 4; ++i) { di[i] = ((const uint4*)xd)[i]; sj[i] = ((const uint4*)xs)[i]; }
        __bf16* hrow = &sh_h[r * HPITCH];
        #pragma unroll
        for (int i = 0; i < 4; ++i) ((uint4*)&hrow[q * 32])[i] = di[i];   // xi raw
        #pragma unroll
        for (int i = 0; i < 4; ++i) {
            __bf16 a[8], b[8], ov[8];
            __builtin_memcpy(a, &di[i], 16);
            __builtin_memcpy(b, &sj[i], 16);
            #pragma unroll
            for (int j = 0; j < 8; ++j) ov[j] = (__bf16)((float)b[j] - (float)a[j]);
            uint4 o;
            __builtin_memcpy(&o, ov, 16);
            ((uint4*)&hrow[128 + q * 32])[i] = o;
        }
    }

    if (tid < MT) atomicAdd(&cnt[s_dst[tid]], 1.0f);

    const int w    = tid >> 6;
    const int lane = tid & 63;
    const int lr   = lane & 15;
    const int lq   = lane >> 4;

    // ---- stages 1 & 2: h = relu(scale * (h @ W^T) + c), in-place in sh_h
    #pragma unroll 1
    for (int stage = 0; stage < 2; ++stage) {
        const __bf16* Wp = (stage == 0) ? W1 : W2;
        const int wm = w >> 2, wn = w & 3;          // 2 x 4 wave grid
        const int m_base = wm * 64, n_base = wn * 64;
        f32x4 acc[4][4];
        #pragma unroll
        for (int i = 0; i < 4; ++i)
            #pragma unroll
            for (int j = 0; j < 4; ++j) acc[i][j] = (f32x4){0.f, 0.f, 0.f, 0.f};

        #pragma unroll 1
        for (int kc = 0; kc < 4; ++kc) {
            __syncthreads();
            {   // stage W chunk [256 n][64 k] into LDS
                const int n    = tid >> 1;
                const int half = (tid & 1) * 32;
                const uint4* s4 = (const uint4*)(Wp + (size_t)n * HH + kc * 64 + half);
                uint4* d4 = (uint4*)&sh_w[n * WPITCH + half];
                #pragma unroll
                for (int i = 0; i < 4; ++i) d4[i] = s4[i];
            }
            __syncthreads();
            #pragma unroll
            for (int kk = 0; kk < 2; ++kk) {
                bf16x8 af[4], bfr[4];
                #pragma unroll
                for (int i = 0; i < 4; ++i)
                    af[i] = *(const bf16x8*)&sh_h[(m_base + i * 16 + lr) * HPITCH + kc * 64 + kk * 32 + lq * 8];
                #pragma unroll
                for (int j = 0; j < 4; ++j)
                    bfr[j] = *(const bf16x8*)&sh_w[(n_base + j * 16 + lr) * WPITCH + kk * 32 + lq * 8];
                #pragma unroll
                for (int i = 0; i < 4; ++i)
                    #pragma unroll
                    for (int j = 0; j < 4; ++j)
                        acc[i][j] = __builtin_amdgcn_mfma_f32_16x16x32_bf16(af[i], bfr[j], acc[i][j], 0, 0, 0);
            }
        }
        __syncthreads();   // all reads of sh_h done -> safe to overwrite in place
        #pragma unroll
        for (int j = 0; j < 4; ++j) {
            const int n = n_base + j * 16 + lr;
            const float sc = s_scale[stage][n];
            const float cc = s_c[stage][n];
            #pragma unroll
            for (int i = 0; i < 4; ++i) {
                #pragma unroll
                for (int r = 0; r < 4; ++r) {
                    const int m = m_base + i * 16 + lq * 4 + r;
                    float v = acc[i][j][r] * sc + cc;
                    sh_h[m * HPITCH + n] = (__bf16)fmaxf(v, 0.0f);
                }
            }
        }
    }

    // ---- stage 3: [128x256] @ W3^T -> [128x128], +b3, atomic scatter-add
    {
        const int wm = w >> 1, wn = w & 1;          // 4 x 2 wave grid
        const int m_base = wm * 32, n_base = wn * 64;
        f32x4 acc[2][4];
        #pragma unroll
        for (int i = 0; i < 2; ++i)
            #pragma unroll
            for (int j = 0; j < 4; ++j) acc[i][j] = (f32x4){0.f, 0.f, 0.f, 0.f};

        #pragma unroll 1
        for (int kc = 0; kc < 4; ++kc) {
            __syncthreads();
            if (tid < 256) {   // W3 chunk [128 n][64 k]
                const int n    = tid >> 1;
                const int half = (tid & 1) * 32;
                const uint4* s4 = (const uint4*)(W3 + (size_t)n * HH + kc * 64 + half);
                uint4* d4 = (uint4*)&sh_w[n * WPITCH + half];
                #pragma unroll
                for (int i = 0; i < 4; ++i) d4[i] = s4[i];
            }
            __syncthreads();
            #pragma unroll
            for (int kk = 0; kk < 2; ++kk) {
                bf16x8 af[2], bfr[4];
                #pragma unroll
                for (int i = 0; i < 2; ++i)
                    af[i] = *(const bf16x8*)&sh_h[(m_base + i * 16 + lr) * HPITCH + kc * 64 + kk * 32 + lq * 8];
                #pragma unroll
                for (int j = 0; j < 4; ++j)
                    bfr[j] = *(const bf16x8*)&sh_w[(n_base + j * 16 + lr) * WPITCH + kk * 32 + lq * 8];
                #pragma unroll
                for (int i = 0; i < 2; ++i)
                    #pragma unroll
                    for (int j = 0; j < 4; ++j)
                        acc[i][j] = __builtin_amdgcn_mfma_f32_16x16x32_bf16(af[i], bfr[j], acc[i][j], 0, 0, 0);
            }
        }
        #pragma unroll
        for (int j = 0; j < 4; ++j) {
            const int n = n_base + j * 16 + lr;
            const float bb = s_b3[n];
            #pragma unroll
            for (int i = 0; i < 2; ++i) {
                #pragma unroll
                for (int r = 0; r < 4; ++r) {
                    const int m = m_base + i * 16 + lq * 4 + r;
                    const int d = s_dst[m];
                    atomicAdd(&accum[(size_t)d * FF + n], acc[i][j][r] + bb);
                }
            }
        }
    }
}

__global__ __launch_bounds__(256) void finalize_kernel(const float* __restrict__ accum,
                                                       const float* __restrict__ cnt,
                                                       float* __restrict__ out)
{
    const int i = blockIdx.x * 256 + threadIdx.x;
    if (i < NN * FF) {
        const int node = i >> 7;
        const float c = fmaxf(cnt[node], 1.0f);
        out[i] = tanhf(accum[i] / c);
    }
}

extern "C" void kernel_launch(void* const* d_in, const int* in_sizes, int n_in,
                              void* d_out, int out_size, void* d_ws, size_t ws_size,
                              hipStream_t stream)
{
    const float* x   = (const float*)d_in[0];
    const int*   ei  = (const int*)d_in[1];
    const float* W1  = (const float*)d_in[2];
    const float* b1  = (const float*)d_in[3];
    const float* g1  = (const float*)d_in[4];
    const float* be1 = (const float*)d_in[5];
    const float* rm1 = (const float*)d_in[6];
    const float* rv1 = (const float*)d_in[7];
    const float* W2  = (const float*)d_in[8];
    const float* b2  = (const float*)d_in[9];
    const float* g2  = (const float*)d_in[10];
    const float* be2 = (const float*)d_in[11];
    const float* rm2 = (const float*)d_in[12];
    const float* rv2 = (const float*)d_in[13];
    const float* W3  = (const float*)d_in[14];
    const float* b3  = (const float*)d_in[15];

    char* ws = (char*)d_ws;
    float* accum = (float*)ws;
    float* cnt   = (float*)(ws + (size_t)NN * FF * 4);
    __bf16* xb   = (__bf16*)(ws + XB_OFF);
    __bf16* w1b  = (__bf16*)(ws + W1B_OFF);
    __bf16* w2b  = (__bf16*)(ws + W2B_OFF);
    __bf16* w3b  = (__bf16*)(ws + W3B_OFF);

    hipMemsetAsync(d_ws, 0, ((size_t)NN * FF + NN) * sizeof(float), stream);
    convert_kernel<<<(CVT_TOTAL / 4 + 255) / 256, 256, 0, stream>>>(x, W1, W2, W3,
                                                                    xb, w1b, w2b, w3b);
    fused_edge_mlp<<<EE / MT, NTHREADS, 0, stream>>>(xb, ei, w1b, b1, g1, be1, rm1, rv1,
                                                     w2b, b2, g2, be2, rm2, rv2, w3b, b3,
                                                     accum, cnt);
    finalize_kernel<<<(NN * FF + 255) / 256, 256, 0, stream>>>(accum, cnt, (float*)d_out);
}

// Round 3
// 384.069 us; speedup vs baseline: 1.0038x; 1.0038x over previous
//
#include <hip/hip_runtime.h>
#include <math.h>

#define NN 20000
#define EE 320000
#define FF 128
#define HH 256
#define HPITCH 264   // 256 + 8 bf16 pad
#define WPITCH 72    // 64 + 8 bf16 pad
#define TPITCH 130   // fp32 epilogue tile pitch (130 % 32 == 2 -> 2-way, free)
#define MT 128       // edges per block
#define NTHREADS 512

typedef __bf16 bf16x8 __attribute__((ext_vector_type(8)));
typedef float  f32x4  __attribute__((ext_vector_type(4)));

// ---- workspace layout (bytes) ----
// cnt_i : NN int32            @ 0
// wptr  : NN int32            @ 80,000
// ssrc  : EE u16              @ 160,000
// sdst  : EE u16              @ 800,000
// xb    : NN*FF bf16          @ 1,440,000
// w1b   : HH*HH bf16          @ 6,560,000
// w2b   : HH*HH bf16          @ 6,691,072
// w3b   : FF*HH bf16          @ 6,822,144   (end 6,887,680)
#define WPTR_OFF 80000
#define SSRC_OFF 160000
#define SDST_OFF 800000
#define XB_OFF   1440000
#define W1B_OFF  6560000
#define W2B_OFF  6691072
#define W3B_OFF  6822144

#define CVT_TOTAL (NN*FF + HH*HH + HH*HH + FF*HH)   // 2,723,840 elements

__global__ __launch_bounds__(256) void convert_kernel(
    const float* __restrict__ x,  const float* __restrict__ W1,
    const float* __restrict__ W2, const float* __restrict__ W3,
    __bf16* __restrict__ xb, __bf16* __restrict__ w1b,
    __bf16* __restrict__ w2b, __bf16* __restrict__ w3b)
{
    const size_t base = ((size_t)blockIdx.x * 256 + threadIdx.x) * 4;
    if (base >= CVT_TOTAL) return;
    const float* src; __bf16* dst; size_t off;
    if (base < (size_t)NN * FF)                { src = x;  dst = xb;  off = base; }
    else if (base < (size_t)NN*FF + HH*HH)     { src = W1; dst = w1b; off = base - (size_t)NN*FF; }
    else if (base < (size_t)NN*FF + 2*HH*HH)   { src = W2; dst = w2b; off = base - (size_t)NN*FF - HH*HH; }
    else                                       { src = W3; dst = w3b; off = base - (size_t)NN*FF - 2*HH*HH; }
    float4 v = *(const float4*)(src + off);
    __bf16 o[4] = { (__bf16)v.x, (__bf16)v.y, (__bf16)v.z, (__bf16)v.w };
    __builtin_memcpy(dst + off, o, 8);
}

__global__ __launch_bounds__(256) void hist_kernel(const int* __restrict__ eidx,
                                                   int* __restrict__ cnt)
{
    const int e = blockIdx.x * 256 + threadIdx.x;
    if (e < EE) atomicAdd(&cnt[eidx[EE + e]], 1);
}

// exclusive prefix sum of cnt[0..NN) -> wptr, single block of 1024 threads
__global__ __launch_bounds__(1024) void scan_kernel(const int* __restrict__ cnt,
                                                    int* __restrict__ wptr)
{
    __shared__ int s_part[1024];
    const int t = threadIdx.x;
    const int base = t * 20;
    int loc[20];
    int sum = 0;
    #pragma unroll
    for (int i = 0; i < 20; ++i) {
        const int idx = base + i;
        const int v = (idx < NN) ? cnt[idx] : 0;
        loc[i] = sum;
        sum += v;
    }
    s_part[t] = sum;
    __syncthreads();
    for (int d = 1; d < 1024; d <<= 1) {
        const int v = (t >= d) ? s_part[t - d] : 0;
        __syncthreads();
        s_part[t] += v;
        __syncthreads();
    }
    const int excl = s_part[t] - sum;
    #pragma unroll
    for (int i = 0; i < 20; ++i) {
        const int idx = base + i;
        if (idx < NN) wptr[idx] = excl + loc[i];
    }
}

__global__ __launch_bounds__(256) void scatter_kernel(const int* __restrict__ eidx,
                                                      int* __restrict__ wptr,
                                                      unsigned short* __restrict__ ssrc,
                                                      unsigned short* __restrict__ sdst)
{
    const int e = blockIdx.x * 256 + threadIdx.x;
    if (e < EE) {
        const int d = eidx[EE + e];
        const int pos = atomicAdd(&wptr[d], 1);
        ssrc[pos] = (unsigned short)eidx[e];
        sdst[pos] = (unsigned short)d;
    }
}

__global__ __launch_bounds__(NTHREADS) void fused_edge_mlp(
    const __bf16* __restrict__ x,
    const unsigned short* __restrict__ ssrc,
    const unsigned short* __restrict__ sdst,
    const __bf16* __restrict__ W1,
    const float*  __restrict__ b1, const float* __restrict__ g1,
    const float*  __restrict__ be1, const float* __restrict__ rm1,
    const float*  __restrict__ rv1,
    const __bf16* __restrict__ W2,
    const float*  __restrict__ b2, const float* __restrict__ g2,
    const float*  __restrict__ be2, const float* __restrict__ rm2,
    const float*  __restrict__ rv2,
    const __bf16* __restrict__ W3,
    float* __restrict__ outp)
{
    __shared__ __align__(16) __bf16 sh_h[MT * HPITCH];   // 67584 B (also reused as fp32 tile 128x130)
    __shared__ __align__(16) __bf16 sh_w[HH * WPITCH];   // 36864 B
    __shared__ float s_scale[2][HH];
    __shared__ float s_c[2][HH];
    __shared__ int   s_dst[MT];
    __shared__ int   s_src[MT];

    const int tid = threadIdx.x;
    const int e0  = blockIdx.x * MT;

    if (tid < MT) {
        s_src[tid] = (int)ssrc[e0 + tid];
        s_dst[tid] = (int)sdst[e0 + tid];
    }
    if (tid < HH) {
        float sc1 = g1[tid] * rsqrtf(rv1[tid] + 1e-5f);
        s_scale[0][tid] = sc1;
        s_c[0][tid] = (b1[tid] - rm1[tid]) * sc1 + be1[tid];
        float sc2 = g2[tid] * rsqrtf(rv2[tid] + 1e-5f);
        s_scale[1][tid] = sc2;
        s_c[1][tid] = (b2[tid] - rm2[tid]) * sc2 + be2[tid];
    }
    __syncthreads();

    // ---- gather & concat: sh_h[r][0:128] = x[dst], sh_h[r][128:256] = x[src]-x[dst]
    {
        const int r = tid >> 2;       // 0..127
        const int q = tid & 3;        // 32-col quarter
        const __bf16* xd = x + (size_t)s_dst[r] * FF + q * 32;
        const __bf16* xs = x + (size_t)s_src[r] * FF + q * 32;
        uint4 di[4], sj[4];
        #pragma unroll
        for (int i = 0; i < 4; ++i) { di[i] = ((const uint4*)xd)[i]; sj[i] = ((const uint4*)xs)[i]; }
        __bf16* hrow = &sh_h[r * HPITCH];
        #pragma unroll
        for (int i = 0; i < 4; ++i) ((uint4*)&hrow[q * 32])[i] = di[i];   // xi raw
        #pragma unroll
        for (int i = 0; i < 4; ++i) {
            __bf16 a[8], b[8], ov[8];
            __builtin_memcpy(a, &di[i], 16);
            __builtin_memcpy(b, &sj[i], 16);
            #pragma unroll
            for (int j = 0; j < 8; ++j) ov[j] = (__bf16)((float)b[j] - (float)a[j]);
            uint4 o;
            __builtin_memcpy(&o, ov, 16);
            ((uint4*)&hrow[128 + q * 32])[i] = o;
        }
    }

    const int w    = tid >> 6;
    const int lane = tid & 63;
    const int lr   = lane & 15;
    const int lq   = lane >> 4;

    // ---- stages 1 & 2: h = relu(scale * (h @ W^T) + c), in-place in sh_h
    #pragma unroll 1
    for (int stage = 0; stage < 2; ++stage) {
        const __bf16* Wp = (stage == 0) ? W1 : W2;
        const int wm = w >> 2, wn = w & 3;          // 2 x 4 wave grid
        const int m_base = wm * 64, n_base = wn * 64;
        f32x4 acc[4][4];
        #pragma unroll
        for (int i = 0; i < 4; ++i)
            #pragma unroll
            for (int j = 0; j < 4; ++j) acc[i][j] = (f32x4){0.f, 0.f, 0.f, 0.f};

        #pragma unroll 1
        for (int kc = 0; kc < 4; ++kc) {
            __syncthreads();
            {   // stage W chunk [256 n][64 k] into LDS
                const int n    = tid >> 1;
                const int half = (tid & 1) * 32;
                const uint4* s4 = (const uint4*)(Wp + (size_t)n * HH + kc * 64 + half);
                uint4* d4 = (uint4*)&sh_w[n * WPITCH + half];
                #pragma unroll
                for (int i = 0; i < 4; ++i) d4[i] = s4[i];
            }
            __syncthreads();
            #pragma unroll
            for (int kk = 0; kk < 2; ++kk) {
                bf16x8 af[4], bfr[4];
                #pragma unroll
                for (int i = 0; i < 4; ++i)
                    af[i] = *(const bf16x8*)&sh_h[(m_base + i * 16 + lr) * HPITCH + kc * 64 + kk * 32 + lq * 8];
                #pragma unroll
                for (int j = 0; j < 4; ++j)
                    bfr[j] = *(const bf16x8*)&sh_w[(n_base + j * 16 + lr) * WPITCH + kk * 32 + lq * 8];
                #pragma unroll
                for (int i = 0; i < 4; ++i)
                    #pragma unroll
                    for (int j = 0; j < 4; ++j)
                        acc[i][j] = __builtin_amdgcn_mfma_f32_16x16x32_bf16(af[i], bfr[j], acc[i][j], 0, 0, 0);
            }
        }
        __syncthreads();   // all reads of sh_h done -> safe to overwrite in place
        #pragma unroll
        for (int j = 0; j < 4; ++j) {
            const int n = n_base + j * 16 + lr;
            const float sc = s_scale[stage][n];
            const float cc = s_c[stage][n];
            #pragma unroll
            for (int i = 0; i < 4; ++i) {
                #pragma unroll
                for (int r = 0; r < 4; ++r) {
                    const int m = m_base + i * 16 + lq * 4 + r;
                    float v = acc[i][j][r] * sc + cc;
                    sh_h[m * HPITCH + n] = (__bf16)fmaxf(v, 0.0f);
                }
            }
        }
    }

    // ---- stage 3: [128x256] @ W3^T -> [128x128], LDS tile, segmented scatter-add
    {
        const int wm = w >> 1, wn = w & 1;          // 4 x 2 wave grid
        const int m_base = wm * 32, n_base = wn * 64;
        f32x4 acc[2][4];
        #pragma unroll
        for (int i = 0; i < 2; ++i)
            #pragma unroll
            for (int j = 0; j < 4; ++j) acc[i][j] = (f32x4){0.f, 0.f, 0.f, 0.f};

        #pragma unroll 1
        for (int kc = 0; kc < 4; ++kc) {
            __syncthreads();
            if (tid < 256) {   // W3 chunk [128 n][64 k]
                const int n    = tid >> 1;
                const int half = (tid & 1) * 32;
                const uint4* s4 = (const uint4*)(W3 + (size_t)n * HH + kc * 64 + half);
                uint4* d4 = (uint4*)&sh_w[n * WPITCH + half];
                #pragma unroll
                for (int i = 0; i < 4; ++i) d4[i] = s4[i];
            }
            __syncthreads();
            #pragma unroll
            for (int kk = 0; kk < 2; ++kk) {
                bf16x8 af[2], bfr[4];
                #pragma unroll
                for (int i = 0; i < 2; ++i)
                    af[i] = *(const bf16x8*)&sh_h[(m_base + i * 16 + lr) * HPITCH + kc * 64 + kk * 32 + lq * 8];
                #pragma unroll
                for (int j = 0; j < 4; ++j)
                    bfr[j] = *(const bf16x8*)&sh_w[(n_base + j * 16 + lr) * WPITCH + kk * 32 + lq * 8];
                #pragma unroll
                for (int i = 0; i < 2; ++i)
                    #pragma unroll
                    for (int j = 0; j < 4; ++j)
                        acc[i][j] = __builtin_amdgcn_mfma_f32_16x16x32_bf16(af[i], bfr[j], acc[i][j], 0, 0, 0);
            }
        }

        __syncthreads();   // all K-loop reads of sh_h complete before reuse as fp32 tile
        float* tile = (float*)sh_h;   // 128 x TPITCH fp32 (66560 B <= 67584 B)
        #pragma unroll
        for (int j = 0; j < 4; ++j) {
            const int n = n_base + j * 16 + lr;
            #pragma unroll
            for (int i = 0; i < 2; ++i) {
                #pragma unroll
                for (int r = 0; r < 4; ++r)
                    tile[(m_base + i * 16 + lq * 4 + r) * TPITCH + n] = acc[i][j][r];
            }
        }
        __syncthreads();

        // segmented reduction: sorted dst -> one atomic per (segment, col, chunk)
        {
            const int col = tid & 127;
            const int r0  = (tid >> 7) * 32;       // wave-uniform chunk
            int cur = s_dst[r0];
            float run = 0.f;
            #pragma unroll 1
            for (int r = r0; r < r0 + 32; ++r) {
                const int d = s_dst[r];            // wave-uniform
                if (d != cur) {
                    atomicAdd(&outp[(size_t)cur * FF + col], run);
                    run = 0.f; cur = d;
                }
                run += tile[r * TPITCH + col];
            }
            atomicAdd(&outp[(size_t)cur * FF + col], run);
        }
    }
}

__global__ __launch_bounds__(256) void finalize_kernel(const int* __restrict__ cnt,
                                                       const float* __restrict__ b3,
                                                       float* __restrict__ out)
{
    const int i = blockIdx.x * 256 + threadIdx.x;
    if (i < NN * FF) {
        const float c = fmaxf((float)cnt[i >> 7], 1.0f);
        out[i] = tanhf(out[i] / c + b3[i & 127]);
    }
}

extern "C" void kernel_launch(void* const* d_in, const int* in_sizes, int n_in,
                              void* d_out, int out_size, void* d_ws, size_t ws_size,
                              hipStream_t stream)
{
    const float* x   = (const float*)d_in[0];
    const int*   ei  = (const int*)d_in[1];
    const float* W1  = (const float*)d_in[2];
    const float* b1  = (const float*)d_in[3];
    const float* g1  = (const float*)d_in[4];
    const float* be1 = (const float*)d_in[5];
    const float* rm1 = (const float*)d_in[6];
    const float* rv1 = (const float*)d_in[7];
    const float* W2  = (const float*)d_in[8];
    const float* b2  = (const float*)d_in[9];
    const float* g2  = (const float*)d_in[10];
    const float* be2 = (const float*)d_in[11];
    const float* rm2 = (const float*)d_in[12];
    const float* rv2 = (const float*)d_in[13];
    const float* W3  = (const float*)d_in[14];
    const float* b3  = (const float*)d_in[15];

    char* ws = (char*)d_ws;
    int* cnt_i = (int*)ws;
    int* wptr  = (int*)(ws + WPTR_OFF);
    unsigned short* ssrc = (unsigned short*)(ws + SSRC_OFF);
    unsigned short* sdst = (unsigned short*)(ws + SDST_OFF);
    __bf16* xb  = (__bf16*)(ws + XB_OFF);
    __bf16* w1b = (__bf16*)(ws + W1B_OFF);
    __bf16* w2b = (__bf16*)(ws + W2B_OFF);
    __bf16* w3b = (__bf16*)(ws + W3B_OFF);
    float* outp = (float*)d_out;

    hipMemsetAsync(cnt_i, 0, NN * sizeof(int), stream);
    hipMemsetAsync(d_out, 0, (size_t)NN * FF * sizeof(float), stream);

    convert_kernel<<<(CVT_TOTAL / 4 + 255) / 256, 256, 0, stream>>>(x, W1, W2, W3,
                                                                    xb, w1b, w2b, w3b);
    hist_kernel<<<(EE + 255) / 256, 256, 0, stream>>>(ei, cnt_i);
    scan_kernel<<<1, 1024, 0, stream>>>(cnt_i, wptr);
    scatter_kernel<<<(EE + 255) / 256, 256, 0, stream>>>(ei, wptr, ssrc, sdst);
    fused_edge_mlp<<<EE / MT, NTHREADS, 0, stream>>>(xb, ssrc, sdst,
                                                     w1b, b1, g1, be1, rm1, rv1,
                                                     w2b, b2, g2, be2, rm2, rv2,
                                                     w3b, outp);
    finalize_kernel<<<(NN * FF + 255) / 256, 256, 0, stream>>>(cnt_i, b3, outp);
}